// Round 4
// baseline (573.816 us; speedup 1.0000x reference)
//
#include <hip/hip_runtime.h>

#define H 256
#define W 256
#define BATCH 8
#define CIN 16
#define TW 64
#define TH 8
#define HWC (TW + 2)        // 66 halo cols
#define HHC (TH + 2)        // 10 halo rows
#define NHALO (HWC * HHC)   // 660 halo pixels
#define FIX_CAP 16384
#define GAP_TAU 2e-3f

// LDS layout (bytes): bufB dbuf 16384 | xhL 10560 | xlL 10560 | gsL 2640
//                     | sw 256 | bias 256 | red 32  = 40688  -> 3 blocks/CU
#define OFF_XH   16384
#define OFF_XL   26944
#define OFF_GS   37504
#define OFF_SW   40144
#define OFF_BIAS 40400
#define OFF_RED  40656
#define SMEM_BYTES 40688

typedef __attribute__((ext_vector_type(4))) int i32x4;   // 16 int8 for MFMA A/B, or i32 C/D

__device__ __forceinline__ void gload_lds16(const void* g, void* l) {
    __builtin_amdgcn_global_load_lds(
        (const __attribute__((address_space(1))) unsigned int*)g,
        (__attribute__((address_space(3))) unsigned int*)l, 16, 0, 0);
}

// weight [oc=n][ic=k][3][3] fp32 -> two-term int8, fragment-major for conflict-free LDS reads:
//   wt byte addr = ((tap*2+term)*4 + nt)*1024 + (kq*16 + (n&15))*16 + (k&15)
//   term 0: wh = rn(w*127/wmax[n]); term 1: wl = rn((w*inv - wh)*128)
// sw_ws[n] = wmax[n]/127. Also zeroes fix_cnt.
__global__ void wprep_kernel(const float* __restrict__ w, char* __restrict__ wt,
                             float* __restrict__ sw_ws, unsigned* __restrict__ fix_cnt) {
    const int n = blockIdx.x;        // 64 blocks
    const int k = threadIdx.x;       // 64 threads
    if (n == 0 && k == 0) fix_cnt[0] = 0u;

    float v[9];
    float m = 0.f;
#pragma unroll
    for (int t = 0; t < 9; ++t) {
        v[t] = w[(n * 64 + k) * 9 + t];
        m = fmaxf(m, fabsf(v[t]));
    }
#pragma unroll
    for (int s = 1; s < 64; s <<= 1) m = fmaxf(m, __shfl_xor(m, s, 64));
    const float inv = (m > 0.f) ? (127.f / m) : 0.f;
    if (k == 0) sw_ws[n] = m * (1.f / 127.f);

    const int nt = n >> 4, nl = n & 15, kq = k >> 4, j = k & 15;
    const int lane16 = (kq * 16 + nl) * 16 + j;
#pragma unroll
    for (int t = 0; t < 9; ++t) {
        float f = v[t] * inv;
        int h = __float2int_rn(f);
        int l = __float2int_rn((f - (float)h) * 128.f);
        wt[((t * 2 + 0) * 4 + nt) * 1024 + lane16] = (char)h;
        wt[((t * 2 + 1) * 4 + nt) * 1024 + lane16] = (char)l;
    }
}

__global__ __launch_bounds__(512, 4) void ssconv_i8_kernel(
    const float* __restrict__ x, const int* __restrict__ gidx,
    const char* __restrict__ wt, const float* __restrict__ sw_ws,
    const float* __restrict__ bias,
    float* __restrict__ out_sel, float* __restrict__ out_idx,
    unsigned* __restrict__ fix_cnt, unsigned* __restrict__ fix_list)
{
    __shared__ __align__(16) char smem[SMEM_BYTES];
    char*  bufB  = smem;                       // 2 x 8192, double buffer
    char*  xhL   = smem + OFF_XH;
    char*  xlL   = smem + OFF_XL;
    int*   gsL   = (int*)(smem + OFF_GS);
    float* swdL  = (float*)(smem + OFF_SW);
    float* biasL = (float*)(smem + OFF_BIAS);
    float* redL  = (float*)(smem + OFF_RED);

    const int tid  = threadIdx.x;
    const int x0   = blockIdx.x * TW;
    const int y0   = blockIdx.y * TH;
    const int bz   = blockIdx.z;
    const int wvid = tid >> 6;            // wave 0..7 -> tile row
    const int L    = tid & 63;
    const int q    = L >> 4;              // quad = K-chunk = in-group slot
    const int lm   = L & 15;

    // ---- issue B(tap=0) -> buf0 (8192 B, 16 B/thread) ----
    gload_lds16(wt + tid * 16, bufB + tid * 16);

    if (tid < 64) { swdL[tid] = sw_ws[tid]; biasL[tid] = bias[tid]; }

    // ---- phase 1: load halo into regs + block absmax reduce ----
    float4 av[2][4];
    int gv[2];
    float am = 0.f;
#pragma unroll
    for (int s = 0; s < 2; ++s) {
        av[s][0] = av[s][1] = av[s][2] = av[s][3] = make_float4(0, 0, 0, 0);
        gv[s] = 0;
        int i = tid + s * 512;
        if (i < NHALO) {
            int r = i / HWC, c = i - r * HWC;
            int hy = y0 + r - 1, hx = x0 + c - 1;
            if (hy >= 0 && hy < H && hx >= 0 && hx < W) {
                const float4* src = (const float4*)(x + (((size_t)bz * H + hy) * W + hx) * CIN);
                av[s][0] = src[0]; av[s][1] = src[1]; av[s][2] = src[2]; av[s][3] = src[3];
                gv[s] = gidx[((size_t)bz * H + hy) * W + hx];
            }
#pragma unroll
            for (int j = 0; j < 4; ++j)
                am = fmaxf(am, fmaxf(fmaxf(fabsf(av[s][j].x), fabsf(av[s][j].y)),
                                     fmaxf(fabsf(av[s][j].z), fabsf(av[s][j].w))));
        }
    }
#pragma unroll
    for (int s = 1; s < 64; s <<= 1) am = fmaxf(am, __shfl_xor(am, s, 64));
    if (L == 0) redL[wvid] = am;
    __syncthreads();
    float bm = redL[0];
#pragma unroll
    for (int wv = 1; wv < 8; ++wv) bm = fmaxf(bm, redL[wv]);
    const float qinv = (bm > 0.f) ? (127.f / bm) : 0.f;
    const float sB   = bm * (1.f / 127.f);

    // ---- phase 2: quantize regs -> two-term int8 in LDS ----
#pragma unroll
    for (int s = 0; s < 2; ++s) {
        int i = tid + s * 512;
        if (i < NHALO) {
            unsigned hw[4], lw[4];
#pragma unroll
            for (int j = 0; j < 4; ++j) {
                float fs[4] = {av[s][j].x, av[s][j].y, av[s][j].z, av[s][j].w};
                unsigned hword = 0, lword = 0;
#pragma unroll
                for (int e = 0; e < 4; ++e) {
                    float f_ = fs[e] * qinv;
                    int h_ = __float2int_rn(f_);
                    int l_ = __float2int_rn((f_ - (float)h_) * 128.f);
                    hword |= ((unsigned)(h_ & 255)) << (8 * e);
                    lword |= ((unsigned)(l_ & 255)) << (8 * e);
                }
                hw[j] = hword; lw[j] = lword;
            }
            *(uint4*)&xhL[(size_t)i * 16] = make_uint4(hw[0], hw[1], hw[2], hw[3]);
            *(uint4*)&xlL[(size_t)i * 16] = make_uint4(lw[0], lw[1], lw[2], lw[3]);
            gsL[i] = gv[s];
        }
    }
    __syncthreads();   // halo ready; also drains B(0) prefetch vmcnt

    i32x4 acc1[4][4] = {};   // xh*wh (int32 exact)
    i32x4 acc2[4][4] = {};   // xh*wl + xl*wh (int32 exact, scaled 1/128)

    // ---- main loop: per-tap B double-buffer, conflict-free frag reads ----
#pragma unroll 1
    for (int tap = 0; tap < 9; ++tap) {
        if (tap < 8)   // prefetch next tap's B into the other half (in flight over MFMAs)
            gload_lds16(wt + (size_t)(tap + 1) * 8192 + tid * 16,
                        bufB + ((tap + 1) & 1) * 8192 + tid * 16);

        const char* bB = bufB + (tap & 1) * 8192;
        const int dy = tap / 3, dx = tap - dy * 3;
        const int hbase = (wvid + dy) * HWC + lm + dx;

        i32x4 bh[4], bl[4];
#pragma unroll
        for (int nt = 0; nt < 4; ++nt) {
            bh[nt] = *(const i32x4*)(bB + nt * 1024 + L * 16);
            bl[nt] = *(const i32x4*)(bB + 4096 + nt * 1024 + L * 16);
        }
#pragma unroll
        for (int m = 0; m < 4; ++m) {
            int hb = hbase + 16 * m;
            int gg = gsL[hb];
            i32x4 ah = *(const i32x4*)&xhL[(size_t)hb * 16];
            i32x4 al = *(const i32x4*)&xlL[(size_t)hb * 16];
            bool keep = (gg == q);
            i32x4 z = {};
            i32x4 a0 = keep ? ah : z;
            i32x4 a1 = keep ? al : z;
#pragma unroll
            for (int nt = 0; nt < 4; ++nt) {
                acc1[m][nt] = __builtin_amdgcn_mfma_i32_16x16x64_i8(a0, bh[nt], acc1[m][nt], 0, 0, 0);
                acc2[m][nt] = __builtin_amdgcn_mfma_i32_16x16x64_i8(a0, bl[nt], acc2[m][nt], 0, 0, 0);
                acc2[m][nt] = __builtin_amdgcn_mfma_i32_16x16x64_i8(a1, bh[nt], acc2[m][nt], 0, 0, 0);
            }
        }
        __syncthreads();   // everyone done reading bB; prefetch landed (vmcnt drained)
    }

    // ---- epilogue: all-register. channel n = nt*16+lm -> out-group = nt, c = lm.
    //      pixel: row = wvid, col = m*16 + q*4 + r  (C/D: col=lane&15 -> channel,
    //      row=(lane>>4)*4+reg -> pixel). Cluster-of-16 shuffle maxout, no LDS. ----
    float swb[4], bsr[4];
#pragma unroll
    for (int nt = 0; nt < 4; ++nt) {
        swb[nt] = sB * swdL[nt * 16 + lm];
        bsr[nt] = biasL[nt * 16 + lm];
    }

    const int gy = y0 + wvid;
#pragma unroll
    for (int m = 0; m < 4; ++m) {
#pragma unroll
        for (int r = 0; r < 4; ++r) {
            float v0 = swb[0] * ((float)acc1[m][0][r] + (float)acc2[m][0][r] * (1.f / 128.f)) + bsr[0];
            float v1 = swb[1] * ((float)acc1[m][1][r] + (float)acc2[m][1][r] * (1.f / 128.f)) + bsr[1];
            float v2 = swb[2] * ((float)acc1[m][2][r] + (float)acc2[m][2][r] * (1.f / 128.f)) + bsr[2];
            float v3 = swb[3] * ((float)acc1[m][3][r] + (float)acc2[m][3][r] * (1.f / 128.f)) + bsr[3];

            float g0 = v0, g1 = v1, g2 = v2, g3 = v3;
#pragma unroll
            for (int s = 1; s < 16; s <<= 1) {
                g0 = fmaxf(g0, __shfl_xor(g0, s, 64));
                g1 = fmaxf(g1, __shfl_xor(g1, s, 64));
                g2 = fmaxf(g2, __shfl_xor(g2, s, 64));
                g3 = fmaxf(g3, __shfl_xor(g3, s, 64));
            }
            int bg = 0; float best = g0;
            if (g1 > best) { best = g1; bg = 1; }
            if (g2 > best) { best = g2; bg = 2; }
            if (g3 > best) { best = g3; bg = 3; }

            float selv = (bg == 0) ? v0 : (bg == 1) ? v1 : (bg == 2) ? v2 : v3;

            const int gx = x0 + m * 16 + q * 4 + r;
            const size_t opix = ((size_t)bz * H + gy) * W + gx;
            out_sel[opix * 16 + lm] = selv;

            if (lm == 0) {
                out_idx[opix] = (float)bg;
                float o1v = (bg == 0) ? g1 : g0;
                float o2v = (bg <= 1) ? g2 : g1;
                float o3v = (bg <= 2) ? g3 : g2;
                float second = fmaxf(o1v, fmaxf(o2v, o3v));
                if (best - second < GAP_TAU) {
                    unsigned slot = atomicAdd(fix_cnt, 1u);
                    if (slot < FIX_CAP) fix_list[slot] = (unsigned)opix;
                }
            }
        }
    }
}

// fp64 exact recompute of flagged pixels; one wave per pixel, lane = oc
__global__ void fixup_kernel(const float* __restrict__ x, const int* __restrict__ gidx,
                             const float* __restrict__ w, const float* __restrict__ bias,
                             float* __restrict__ out_sel, float* __restrict__ out_idx,
                             const unsigned* __restrict__ fix_cnt,
                             const unsigned* __restrict__ fix_list)
{
    unsigned n = *fix_cnt;
    if (n > FIX_CAP) n = FIX_CAP;
    const int lane = threadIdx.x & 63;
    const int nwaves = gridDim.x * (blockDim.x >> 6);
    unsigned widx = blockIdx.x * (blockDim.x >> 6) + (threadIdx.x >> 6);

    for (; widx < n; widx += nwaves) {
        unsigned opix = fix_list[widx];
        int b  = opix >> 16;
        int y  = (opix >> 8) & 255;
        int xc = opix & 255;
        double acc = (double)bias[lane];
        for (int dy = 0; dy < 3; ++dy) {
            int yy = y + dy - 1;
            if (yy < 0 || yy >= H) continue;
            for (int dx = 0; dx < 3; ++dx) {
                int xx = xc + dx - 1;
                if (xx < 0 || xx >= W) continue;
                size_t pix = ((size_t)b * H + yy) * W + xx;
                int g = gidx[pix];
                const float* xp = x + pix * 16;
                const float* wp = w + (size_t)(lane * 64 + g * 16) * 9 + (dy * 3 + dx);
#pragma unroll
                for (int c = 0; c < 16; ++c)
                    acc = fma((double)wp[c * 9], (double)xp[c], acc);
            }
        }
        double m = acc;
        m = fmax(m, __shfl_xor(m, 1, 64));
        m = fmax(m, __shfl_xor(m, 2, 64));
        m = fmax(m, __shfl_xor(m, 4, 64));
        m = fmax(m, __shfl_xor(m, 8, 64));
        double g0 = __shfl(m, 0, 64), g1 = __shfl(m, 16, 64);
        double g2 = __shfl(m, 32, 64), g3 = __shfl(m, 48, 64);
        int bg = 0; double bb = g0;
        if (g1 > bb) { bb = g1; bg = 1; }
        if (g2 > bb) { bb = g2; bg = 2; }
        if (g3 > bb) { bb = g3; bg = 3; }
        if ((lane >> 4) == bg) out_sel[(size_t)opix * 16 + (lane & 15)] = (float)acc;
        if (lane == 0) out_idx[opix] = (float)bg;
    }
}

extern "C" void kernel_launch(void* const* d_in, const int* in_sizes, int n_in,
                              void* d_out, int out_size, void* d_ws, size_t ws_size,
                              hipStream_t stream) {
    const float* x    = (const float*)d_in[0];
    const int*   gidx = (const int*)d_in[1];
    const float* w    = (const float*)d_in[2];
    const float* bias = (const float*)d_in[3];

    char*     wt       = (char*)d_ws;                              // 73728 B
    float*    sw_ws    = (float*)((char*)d_ws + 73728);            // 256 B
    unsigned* fix_cnt  = (unsigned*)((char*)d_ws + 73984);         // 16 B
    unsigned* fix_list = (unsigned*)((char*)d_ws + 74000);         // 64 KB

    float* out_sel = (float*)d_out;                               // 8*256*256*16
    float* out_idx = (float*)d_out + (size_t)BATCH * H * W * CIN; // 8*256*256

    wprep_kernel<<<64, 64, 0, stream>>>(w, wt, sw_ws, fix_cnt);

    dim3 grid(W / TW, H / TH, BATCH);   // 4 x 32 x 8 = 1024 blocks
    ssconv_i8_kernel<<<grid, 512, 0, stream>>>(x, gidx, wt, sw_ws, bias,
                                               out_sel, out_idx, fix_cnt, fix_list);
    fixup_kernel<<<256, 256, 0, stream>>>(x, gidx, w, bias, out_sel, out_idx,
                                          fix_cnt, fix_list);
}

// Round 5
// 215.298 us; speedup vs baseline: 2.6652x; 2.6652x over previous
//
#include <hip/hip_runtime.h>

#define H 256
#define W 256
#define BATCH 8
#define CIN 16
#define TW 32
#define TH 4
#define HWC (TW + 2)        // 34 halo cols
#define HHC (TH + 2)        // 6 halo rows
#define NHALO (HWC * HHC)   // 204 halo pixels
#define FIX_CAP 16384
#define GAP_TAU 2e-3f

// LDS layout (bytes): bufB dbuf 16384 | xh 3264 | xl 3264 | gs 816
//                     | sw 256 | bias 256 | red 16 = 24256 -> 3+ blocks/CU
#define OFF_XH   16384
#define OFF_XL   19648
#define OFF_GS   22912
#define OFF_SW   23728
#define OFF_BIAS 23984
#define OFF_RED  24240
#define SMEM_BYTES 24256

typedef __attribute__((ext_vector_type(4))) int i32x4;   // 16 int8 for MFMA A/B, or i32 C/D

__device__ __forceinline__ void gload_lds16(const void* g, void* l) {
    __builtin_amdgcn_global_load_lds(
        (const __attribute__((address_space(1))) unsigned int*)g,
        (__attribute__((address_space(3))) unsigned int*)l, 16, 0, 0);
}

// weight [oc=n][ic=k][3][3] fp32 -> two-term int8, fragment-major for conflict-free LDS reads:
//   wt byte addr = ((tap*2+term)*4 + nt)*1024 + (kq*16 + (n&15))*16 + (k&15)
//   term 0: wh = rn(w*127/wmax[n]); term 1: wl = rn((w*inv - wh)*128)
// sw_ws[n] = wmax[n]/127. Also zeroes fix_cnt.
__global__ void wprep_kernel(const float* __restrict__ w, char* __restrict__ wt,
                             float* __restrict__ sw_ws, unsigned* __restrict__ fix_cnt) {
    const int n = blockIdx.x;        // 64 blocks
    const int k = threadIdx.x;       // 64 threads
    if (n == 0 && k == 0) fix_cnt[0] = 0u;

    float v[9];
    float m = 0.f;
#pragma unroll
    for (int t = 0; t < 9; ++t) {
        v[t] = w[(n * 64 + k) * 9 + t];
        m = fmaxf(m, fabsf(v[t]));
    }
#pragma unroll
    for (int s = 1; s < 64; s <<= 1) m = fmaxf(m, __shfl_xor(m, s, 64));
    const float inv = (m > 0.f) ? (127.f / m) : 0.f;
    if (k == 0) sw_ws[n] = m * (1.f / 127.f);

    const int nt = n >> 4, nl = n & 15, kq = k >> 4, j = k & 15;
    const int lane16 = (kq * 16 + nl) * 16 + j;
#pragma unroll
    for (int t = 0; t < 9; ++t) {
        float f = v[t] * inv;
        int h = __float2int_rn(f);
        int l = __float2int_rn((f - (float)h) * 128.f);
        wt[((t * 2 + 0) * 4 + nt) * 1024 + lane16] = (char)h;
        wt[((t * 2 + 1) * 4 + nt) * 1024 + lane16] = (char)l;
    }
}

__global__ __launch_bounds__(256, 3) void ssconv_i8_kernel(
    const float* __restrict__ x, const int* __restrict__ gidx,
    const char* __restrict__ wt, const float* __restrict__ sw_ws,
    const float* __restrict__ bias,
    float* __restrict__ out_sel, float* __restrict__ out_idx,
    unsigned* __restrict__ fix_cnt, unsigned* __restrict__ fix_list)
{
    __shared__ __align__(16) char smem[SMEM_BYTES];
    char*  bufB  = smem;                       // 2 x 8192, double buffer
    char*  xhL   = smem + OFF_XH;
    char*  xlL   = smem + OFF_XL;
    int*   gsL   = (int*)(smem + OFF_GS);
    float* swdL  = (float*)(smem + OFF_SW);
    float* biasL = (float*)(smem + OFF_BIAS);
    float* redL  = (float*)(smem + OFF_RED);

    const int tid  = threadIdx.x;
    const int x0   = blockIdx.x * TW;
    const int y0   = blockIdx.y * TH;
    const int bz   = blockIdx.z;
    const int wvid = tid >> 6;            // wave 0..3 -> tile row
    const int L    = tid & 63;
    const int q    = L >> 4;              // quad = K-chunk = in-group slot
    const int lm   = L & 15;

    // ---- issue B(tap=0) -> buf0 (8192 B: 2 x 4KB block-wide issues) ----
#pragma unroll
    for (int it = 0; it < 2; ++it) {
        int seg = it * 4 + wvid;          // 8 segments of 1KB, wave-uniform base
        gload_lds16(wt + seg * 1024 + L * 16, bufB + seg * 1024 + L * 16);
    }

    if (tid < 64) { swdL[tid] = sw_ws[tid]; biasL[tid] = bias[tid]; }

    // ---- phase 1: load halo into regs + block absmax reduce ----
    float4 av0 = make_float4(0, 0, 0, 0), av1 = av0, av2 = av0, av3 = av0;
    int gv = 0;
    float am = 0.f;
    if (tid < NHALO) {
        int r = tid / HWC, c = tid - r * HWC;
        int hy = y0 + r - 1, hx = x0 + c - 1;
        if (hy >= 0 && hy < H && hx >= 0 && hx < W) {
            const float4* src = (const float4*)(x + (((size_t)bz * H + hy) * W + hx) * CIN);
            av0 = src[0]; av1 = src[1]; av2 = src[2]; av3 = src[3];
            gv = gidx[((size_t)bz * H + hy) * W + hx];
        }
        am = fmaxf(fmaxf(fmaxf(fabsf(av0.x), fabsf(av0.y)), fmaxf(fabsf(av0.z), fabsf(av0.w))),
              fmaxf(fmaxf(fmaxf(fabsf(av1.x), fabsf(av1.y)), fmaxf(fabsf(av1.z), fabsf(av1.w))),
              fmaxf(fmaxf(fmaxf(fabsf(av2.x), fabsf(av2.y)), fmaxf(fabsf(av2.z), fabsf(av2.w))),
                    fmaxf(fmaxf(fabsf(av3.x), fabsf(av3.y)), fmaxf(fabsf(av3.z), fabsf(av3.w))))));
    }
#pragma unroll
    for (int s = 1; s < 64; s <<= 1) am = fmaxf(am, __shfl_xor(am, s, 64));
    if (L == 0) redL[wvid] = am;
    __syncthreads();
    float bm = fmaxf(fmaxf(redL[0], redL[1]), fmaxf(redL[2], redL[3]));
    const float qinv = (bm > 0.f) ? (127.f / bm) : 0.f;
    const float sB   = bm * (1.f / 127.f);

    // ---- phase 2: quantize regs -> two-term int8 in LDS ----
    if (tid < NHALO) {
        float fs[16] = {av0.x, av0.y, av0.z, av0.w, av1.x, av1.y, av1.z, av1.w,
                        av2.x, av2.y, av2.z, av2.w, av3.x, av3.y, av3.z, av3.w};
        unsigned hw[4], lw[4];
#pragma unroll
        for (int j = 0; j < 4; ++j) {
            unsigned hword = 0, lword = 0;
#pragma unroll
            for (int e = 0; e < 4; ++e) {
                float f_ = fs[j * 4 + e] * qinv;
                int h_ = __float2int_rn(f_);
                int l_ = __float2int_rn((f_ - (float)h_) * 128.f);
                hword |= ((unsigned)(h_ & 255)) << (8 * e);
                lword |= ((unsigned)(l_ & 255)) << (8 * e);
            }
            hw[j] = hword; lw[j] = lword;
        }
        *(uint4*)&xhL[(size_t)tid * 16] = make_uint4(hw[0], hw[1], hw[2], hw[3]);
        *(uint4*)&xlL[(size_t)tid * 16] = make_uint4(lw[0], lw[1], lw[2], lw[3]);
        gsL[tid] = gv;
    }
    __syncthreads();   // halo ready; also drains B(0) prefetch vmcnt

    i32x4 acc1[2][4] = {};   // xh*wh (int32 exact)
    i32x4 acc2[2][4] = {};   // xh*wl + xl*wh (int32 exact, scaled 1/128)

    // ---- main loop: per-tap B double-buffer, conflict-free frag reads ----
#pragma unroll 1
    for (int tap = 0; tap < 9; ++tap) {
        if (tap < 8) {   // prefetch next tap's B into the other half
            const char* gsrc = wt + (size_t)(tap + 1) * 8192;
            char* ldst = bufB + ((tap + 1) & 1) * 8192;
#pragma unroll
            for (int it = 0; it < 2; ++it) {
                int seg = it * 4 + wvid;
                gload_lds16(gsrc + seg * 1024 + L * 16, ldst + seg * 1024 + L * 16);
            }
        }

        const char* bB = bufB + (tap & 1) * 8192;
        const int dy = tap / 3, dx = tap - dy * 3;
        const int hbase = (wvid + dy) * HWC + lm + dx;

        i32x4 bh[4], bl[4];
#pragma unroll
        for (int nt = 0; nt < 4; ++nt) {
            bh[nt] = *(const i32x4*)(bB + nt * 1024 + L * 16);
            bl[nt] = *(const i32x4*)(bB + 4096 + nt * 1024 + L * 16);
        }
#pragma unroll
        for (int m = 0; m < 2; ++m) {
            int hb = hbase + 16 * m;
            int gg = gsL[hb];
            i32x4 ah = *(const i32x4*)&xhL[(size_t)hb * 16];
            i32x4 al = *(const i32x4*)&xlL[(size_t)hb * 16];
            bool keep = (gg == q);
            i32x4 z = {};
            i32x4 a0 = keep ? ah : z;
            i32x4 a1 = keep ? al : z;
#pragma unroll
            for (int nt = 0; nt < 4; ++nt) {
                acc1[m][nt] = __builtin_amdgcn_mfma_i32_16x16x64_i8(a0, bh[nt], acc1[m][nt], 0, 0, 0);
                acc2[m][nt] = __builtin_amdgcn_mfma_i32_16x16x64_i8(a0, bl[nt], acc2[m][nt], 0, 0, 0);
                acc2[m][nt] = __builtin_amdgcn_mfma_i32_16x16x64_i8(a1, bh[nt], acc2[m][nt], 0, 0, 0);
            }
        }
        __syncthreads();   // everyone done reading bB; prefetch landed (vmcnt drained)
    }

    // ---- epilogue: all-register. channel n = nt*16+lm -> out-group = nt, c = lm.
    //      pixel: row = wvid, col = m*16 + q*4 + r. Cluster-of-16 shuffle maxout. ----
    float swb[4], bsr[4];
#pragma unroll
    for (int nt = 0; nt < 4; ++nt) {
        swb[nt] = sB * swdL[nt * 16 + lm];
        bsr[nt] = biasL[nt * 16 + lm];
    }

    const int gy = y0 + wvid;
#pragma unroll
    for (int m = 0; m < 2; ++m) {
#pragma unroll
        for (int r = 0; r < 4; ++r) {
            float v0 = swb[0] * ((float)acc1[m][0][r] + (float)acc2[m][0][r] * (1.f / 128.f)) + bsr[0];
            float v1 = swb[1] * ((float)acc1[m][1][r] + (float)acc2[m][1][r] * (1.f / 128.f)) + bsr[1];
            float v2 = swb[2] * ((float)acc1[m][2][r] + (float)acc2[m][2][r] * (1.f / 128.f)) + bsr[2];
            float v3 = swb[3] * ((float)acc1[m][3][r] + (float)acc2[m][3][r] * (1.f / 128.f)) + bsr[3];

            float g0 = v0, g1 = v1, g2 = v2, g3 = v3;
#pragma unroll
            for (int s = 1; s < 16; s <<= 1) {
                g0 = fmaxf(g0, __shfl_xor(g0, s, 64));
                g1 = fmaxf(g1, __shfl_xor(g1, s, 64));
                g2 = fmaxf(g2, __shfl_xor(g2, s, 64));
                g3 = fmaxf(g3, __shfl_xor(g3, s, 64));
            }
            int bg = 0; float best = g0;
            if (g1 > best) { best = g1; bg = 1; }
            if (g2 > best) { best = g2; bg = 2; }
            if (g3 > best) { best = g3; bg = 3; }

            float selv = (bg == 0) ? v0 : (bg == 1) ? v1 : (bg == 2) ? v2 : v3;

            const int gx = x0 + m * 16 + q * 4 + r;
            const size_t opix = ((size_t)bz * H + gy) * W + gx;
            out_sel[opix * 16 + lm] = selv;

            if (lm == 0) {
                out_idx[opix] = (float)bg;
                float o1v = (bg == 0) ? g1 : g0;
                float o2v = (bg <= 1) ? g2 : g1;
                float o3v = (bg <= 2) ? g3 : g2;
                float second = fmaxf(o1v, fmaxf(o2v, o3v));
                if (best - second < GAP_TAU) {
                    unsigned slot = atomicAdd(fix_cnt, 1u);
                    if (slot < FIX_CAP) fix_list[slot] = (unsigned)opix;
                }
            }
        }
    }
}

// fp64 exact recompute of flagged pixels; one wave per pixel, lane = oc
__global__ void fixup_kernel(const float* __restrict__ x, const int* __restrict__ gidx,
                             const float* __restrict__ w, const float* __restrict__ bias,
                             float* __restrict__ out_sel, float* __restrict__ out_idx,
                             const unsigned* __restrict__ fix_cnt,
                             const unsigned* __restrict__ fix_list)
{
    unsigned n = *fix_cnt;
    if (n > FIX_CAP) n = FIX_CAP;
    const int lane = threadIdx.x & 63;
    const int nwaves = gridDim.x * (blockDim.x >> 6);
    unsigned widx = blockIdx.x * (blockDim.x >> 6) + (threadIdx.x >> 6);

    for (; widx < n; widx += nwaves) {
        unsigned opix = fix_list[widx];
        int b  = opix >> 16;
        int y  = (opix >> 8) & 255;
        int xc = opix & 255;
        double acc = (double)bias[lane];
        for (int dy = 0; dy < 3; ++dy) {
            int yy = y + dy - 1;
            if (yy < 0 || yy >= H) continue;
            for (int dx = 0; dx < 3; ++dx) {
                int xx = xc + dx - 1;
                if (xx < 0 || xx >= W) continue;
                size_t pix = ((size_t)b * H + yy) * W + xx;
                int g = gidx[pix];
                const float* xp = x + pix * 16;
                const float* wp = w + (size_t)(lane * 64 + g * 16) * 9 + (dy * 3 + dx);
#pragma unroll
                for (int c = 0; c < 16; ++c)
                    acc = fma((double)wp[c * 9], (double)xp[c], acc);
            }
        }
        double m = acc;
        m = fmax(m, __shfl_xor(m, 1, 64));
        m = fmax(m, __shfl_xor(m, 2, 64));
        m = fmax(m, __shfl_xor(m, 4, 64));
        m = fmax(m, __shfl_xor(m, 8, 64));
        double g0 = __shfl(m, 0, 64), g1 = __shfl(m, 16, 64);
        double g2 = __shfl(m, 32, 64), g3 = __shfl(m, 48, 64);
        int bg = 0; double bb = g0;
        if (g1 > bb) { bb = g1; bg = 1; }
        if (g2 > bb) { bb = g2; bg = 2; }
        if (g3 > bb) { bb = g3; bg = 3; }
        if ((lane >> 4) == bg) out_sel[(size_t)opix * 16 + (lane & 15)] = (float)acc;
        if (lane == 0) out_idx[opix] = (float)bg;
    }
}

extern "C" void kernel_launch(void* const* d_in, const int* in_sizes, int n_in,
                              void* d_out, int out_size, void* d_ws, size_t ws_size,
                              hipStream_t stream) {
    const float* x    = (const float*)d_in[0];
    const int*   gidx = (const int*)d_in[1];
    const float* w    = (const float*)d_in[2];
    const float* bias = (const float*)d_in[3];

    char*     wt       = (char*)d_ws;                              // 73728 B
    float*    sw_ws    = (float*)((char*)d_ws + 73728);            // 256 B
    unsigned* fix_cnt  = (unsigned*)((char*)d_ws + 73984);         // 16 B
    unsigned* fix_list = (unsigned*)((char*)d_ws + 74000);         // 64 KB

    float* out_sel = (float*)d_out;                               // 8*256*256*16
    float* out_idx = (float*)d_out + (size_t)BATCH * H * W * CIN; // 8*256*256

    wprep_kernel<<<64, 64, 0, stream>>>(w, wt, sw_ws, fix_cnt);

    dim3 grid(W / TW, H / TH, BATCH);   // 8 x 64 x 8 = 4096 blocks
    ssconv_i8_kernel<<<grid, 256, 0, stream>>>(x, gidx, wt, sw_ws, bias,
                                               out_sel, out_idx, fix_cnt, fix_list);
    fixup_kernel<<<256, 256, 0, stream>>>(x, gidx, w, bias, out_sel, out_idx,
                                          fix_cnt, fix_list);
}